// Round 4
// baseline (3121.345 us; speedup 1.0000x reference)
//
#include <hip/hip_runtime.h>

#define N_NEUR 4096
#define T_STEPS 2048
#define DT 0.001f
#define TAU 10.0f
#define V_TH 100.0f
#define V_R -100.0f
#define DECAY (1.0f - DT / TAU)   // 0.9999f

#define SEG 64                    // time steps per prefix segment
#define NSEG (T_STEPS / SEG)      // 32 segments
#define PRE_BLOCKS (NSEG * (N_NEUR / 256))   // 32 * 16 = 512

// ---------------------------------------------------------------------------
// Spike-impossibility bound (exact-math bootstrap, see theory):
//   A_i = |u0_i| + DT*max_t|prefix_t(x_i)| + TAU*|s0_i|
//   A_i <= 0.1  (all i)  ==>  |u_t,i| <= 0.2 for all t  ==>  no spikes ever,
//   so s_t = decay-only and out = s0 * DECAY^(t+1) (exactly 0 for s0 == 0).
//   Margin to v_th=100 is ~500x, dwarfing fp32 prefix-sum error (~1e-4).
// ---------------------------------------------------------------------------

// ---------------------------------------------------------------------------
// K1 (fused, 2560 blocks x 256):
//  blocks 0..511    : per-neuron per-segment prefix stats of x -> d_ws.
//                     Block b: segment g=b>>4, neurons ((b&15)*256 + tid).
//  blocks 512..2559 : writer, out row t = b-512 := s0 * DECAY^(t+1).
//                     (Exact no-spike solution; overwritten by fallback if
//                     the bound ever fails.)
// ---------------------------------------------------------------------------
__global__ __launch_bounds__(256) void k_pre(const float* __restrict__ x,
                                             const float* __restrict__ s0,
                                             float* __restrict__ out,
                                             float* __restrict__ seg_sum,
                                             float* __restrict__ seg_mx,
                                             float* __restrict__ seg_mn) {
    const int b = (int)blockIdx.x;
    const int tid = (int)threadIdx.x;

    if (b < PRE_BLOCKS) {
        const int g = b >> 4;
        const int i = ((b & 15) << 8) + tid;
        const float* p = x + (size_t)g * SEG * N_NEUR + i;
        float run = 0.f, mx = 0.f, mn = 0.f;
        #pragma unroll
        for (int k = 0; k < SEG; ++k) {
            run += p[(size_t)k * N_NEUR];     // loads independent -> pipelined
            mx = fmaxf(mx, run);
            mn = fminf(mn, run);
        }
        seg_sum[g * N_NEUR + i] = run;
        seg_mx[g * N_NEUR + i] = mx;
        seg_mn[g * N_NEUR + i] = mn;
    } else {
        const int t = b - PRE_BLOCKS;
        const float scale = __powf(DECAY, (float)(t + 1));
        const float4* s4 = (const float4*)s0;
        float4* o4 = (float4*)out + (size_t)t * (N_NEUR / 4);
        #pragma unroll
        for (int p4 = 0; p4 < 4; ++p4) {
            const int c = p4 * 256 + tid;
            float4 v = s4[c];
            v.x *= scale; v.y *= scale; v.z *= scale; v.w *= scale;
            o4[c] = v;
        }
    }
}

// ---------------------------------------------------------------------------
// K2 (single block, 1024 threads): combine segment stats into the global
// bound A_i; if all A_i <= 0.1 -> done (fast exit). Otherwise run the exact
// event-driven sequential simulation and overwrite the whole output.
// NOTE: `bad` uses !(A<=0.1) so NaN/Inf inputs also route to the exact path.
// ---------------------------------------------------------------------------
__global__ __launch_bounds__(1024) void k_check_slow(const float* __restrict__ x,
                                                     const float* __restrict__ W,
                                                     const float* __restrict__ u0,
                                                     const float* __restrict__ s0,
                                                     float* __restrict__ out,
                                                     const float* __restrict__ seg_sum,
                                                     const float* __restrict__ seg_mx,
                                                     const float* __restrict__ seg_mn) {
    __shared__ int sbad;
    const int tid = (int)threadIdx.x;
    if (tid == 0) sbad = 0;
    __syncthreads();

    bool bad = false;
    #pragma unroll
    for (int q = 0; q < 4; ++q) {
        const int i = tid + q * 1024;
        float base = 0.f, mx = 0.f, mn = 0.f;
        #pragma unroll
        for (int g = 0; g < NSEG; ++g) {
            mx = fmaxf(mx, base + seg_mx[g * N_NEUR + i]);
            mn = fminf(mn, base + seg_mn[g * N_NEUR + i]);
            base += seg_sum[g * N_NEUR + i];
        }
        const float A = fabsf(u0[i]) + DT * fmaxf(mx, -mn) + TAU * fabsf(s0[i]);
        bad |= !(A <= 0.1f);              // NaN-safe: NaN -> bad
    }
    if (bad) atomicOr(&sbad, 1);
    __syncthreads();
    if (sbad == 0) return;                // expected path: fast exit

    // ---- exact sequential fallback (never taken for in-distribution data) ----
    __shared__ float u[N_NEUR];
    __shared__ float s[N_NEUR];
    __shared__ int list[N_NEUR];
    __shared__ int cnt;
    for (int m = tid; m < N_NEUR; m += 1024) { u[m] = u0[m]; s[m] = s0[m]; }
    if (tid == 0) cnt = 0;
    __syncthreads();
    for (int t = 0; t < T_STEPS; ++t) {
        #pragma unroll
        for (int q = 0; q < 4; ++q) {
            const int i = tid + q * 1024;
            const float ui = u[i];
            const bool spk = ui >= V_TH;
            float un = ui + DT * (ui * ui + x[(size_t)t * N_NEUR + i] + s[i]);
            if (spk) {
                int p = atomicAdd(&cnt, 1);
                list[p] = i;
                un = V_R;
            }
            u[i] = un;
        }
        __syncthreads();
        const int k = cnt;
        #pragma unroll
        for (int q = 0; q < 4; ++q) {
            const int i = tid + q * 1024;
            float acc = 0.f;
            for (int m = 0; m < k; ++m) acc += W[(size_t)i * N_NEUR + list[m]];
            const float sn = s[i] * DECAY + acc;
            s[i] = sn;
            out[(size_t)t * N_NEUR + i] = sn;
        }
        __syncthreads();
        if (tid == 0) cnt = 0;
        __syncthreads();
    }
}

// ---------------------------------------------------------------------------
// Fallback kernels (round-3 path) used only if ws_size < seg-array needs.
// ---------------------------------------------------------------------------
#define NSCAN 64
#define CH 64
#define NCH (T_STEPS / CH)

__global__ __launch_bounds__(64, 1) void k_scan_fb(const float* __restrict__ x,
                                                   const float* __restrict__ u0,
                                                   const float* __restrict__ s0,
                                                   float* __restrict__ out,
                                                   int* __restrict__ flags) {
    const int b = (int)blockIdx.x;
    const int tid = (int)threadIdx.x;
    if (b >= NSCAN) {
        const int t = b - NSCAN;
        const float scale = __powf(DECAY, (float)(t + 1));
        const float4* s4 = (const float4*)s0;
        float4* o4 = (float4*)out + (size_t)t * (N_NEUR / 4);
        #pragma unroll
        for (int p = 0; p < 16; ++p) {
            const int c = p * 64 + tid;
            float4 v = s4[c];
            v.x *= scale; v.y *= scale; v.z *= scale; v.w *= scale;
            o4[c] = v;
        }
        return;
    }
    const int i = b * 64 + tid;
    const float* xp = x + i;
    float uu = u0[i], ss = s0[i], um = uu;
    float A[CH], B[CH], C[CH];
    auto loadch = [&](float (&dst)[CH], int ck) {
        const float* p = xp + (size_t)ck * CH * N_NEUR;
        #pragma unroll
        for (int k = 0; k < CH; ++k) dst[k] = p[(size_t)k * N_NEUR];
    };
    auto compch = [&](const float (&src)[CH]) {
        #pragma unroll
        for (int k = 0; k < CH; ++k) {
            um = fmaxf(um, uu);
            uu = fmaf(DT, fmaf(uu, uu, src[k] + ss), uu);
            ss *= DECAY;
        }
    };
    loadch(A, 0); loadch(B, 1);
    #pragma unroll 1
    for (int c = 0; c < NCH - 2; c += 3) {
        loadch(C, c + 2); compch(A);
        loadch(A, c + 3); compch(B);
        loadch(B, c + 4); compch(C);
    }
    compch(A); compch(B);
    const unsigned long long any = __ballot(um >= 50.0f);
    if (tid == 0) flags[b] = (any != 0ull) ? 1 : 0;
}

__global__ __launch_bounds__(1024) void k_slow_fb(const float* __restrict__ x,
                                                  const float* __restrict__ W,
                                                  const float* __restrict__ u0,
                                                  const float* __restrict__ s0,
                                                  float* __restrict__ out,
                                                  const int* __restrict__ flags) {
    __shared__ int any;
    const int tid = (int)threadIdx.x;
    if (tid == 0) any = 0;
    __syncthreads();
    if (tid < NSCAN && flags[tid] != 0) any = 1;
    __syncthreads();
    if (any == 0) return;
    __shared__ float u[N_NEUR];
    __shared__ float s[N_NEUR];
    __shared__ int list[N_NEUR];
    __shared__ int cnt;
    for (int m = tid; m < N_NEUR; m += 1024) { u[m] = u0[m]; s[m] = s0[m]; }
    if (tid == 0) cnt = 0;
    __syncthreads();
    for (int t = 0; t < T_STEPS; ++t) {
        #pragma unroll
        for (int q = 0; q < 4; ++q) {
            const int i = tid + q * 1024;
            const float ui = u[i];
            const bool spk = ui >= V_TH;
            float un = ui + DT * (ui * ui + x[(size_t)t * N_NEUR + i] + s[i]);
            if (spk) { int p = atomicAdd(&cnt, 1); list[p] = i; un = V_R; }
            u[i] = un;
        }
        __syncthreads();
        const int k = cnt;
        #pragma unroll
        for (int q = 0; q < 4; ++q) {
            const int i = tid + q * 1024;
            float acc = 0.f;
            for (int m = 0; m < k; ++m) acc += W[(size_t)i * N_NEUR + list[m]];
            const float sn = s[i] * DECAY + acc;
            s[i] = sn;
            out[(size_t)t * N_NEUR + i] = sn;
        }
        __syncthreads();
        if (tid == 0) cnt = 0;
        __syncthreads();
    }
}

// ---------------------------------------------------------------------------
extern "C" void kernel_launch(void* const* d_in, const int* in_sizes, int n_in,
                              void* d_out, int out_size, void* d_ws, size_t ws_size,
                              hipStream_t stream) {
    const float* x  = (const float*)d_in[0];   // [T, N]
    const float* W  = (const float*)d_in[1];   // [N, N]
    const float* u0 = (const float*)d_in[2];   // [N]
    const float* s0 = (const float*)d_in[3];   // [N]
    float* out = (float*)d_out;                // [T, N]

    const size_t seg_elems = (size_t)NSEG * N_NEUR;
    if (ws_size >= 3 * seg_elems * sizeof(float)) {
        float* seg_sum = (float*)d_ws;
        float* seg_mx  = seg_sum + seg_elems;
        float* seg_mn  = seg_mx + seg_elems;
        k_pre<<<PRE_BLOCKS + T_STEPS, 256, 0, stream>>>(x, s0, out,
                                                        seg_sum, seg_mx, seg_mn);
        k_check_slow<<<1, 1024, 0, stream>>>(x, W, u0, s0, out,
                                             seg_sum, seg_mx, seg_mn);
    } else {
        int* flags = (int*)d_ws;
        k_scan_fb<<<NSCAN + T_STEPS, 64, 0, stream>>>(x, u0, s0, out, flags);
        k_slow_fb<<<1, 1024, 0, stream>>>(x, W, u0, s0, out, flags);
    }
}

// Round 5
// 44.857 us; speedup vs baseline: 69.5836x; 69.5836x over previous
//
#include <hip/hip_runtime.h>

#define N_NEUR 4096
#define T_STEPS 2048
#define DT 0.001f
#define TAU 10.0f
#define V_TH 100.0f
#define V_R -100.0f
#define DECAY (1.0f - DT / TAU)   // 0.9999f

#define SEG 64                    // time steps per prefix segment
#define NSEG (T_STEPS / SEG)      // 32 segments
#define BETA (DT * (float)SEG)    // 0.064 — per-segment bootstrap constant
#define PRE_BLOCKS (NSEG * (N_NEUR / 256))   // 512

// ---------------------------------------------------------------------------
// Spike-impossibility proof (segment-wise bootstrap):
// While no spike has occurred, exactly:
//   u_t = u0 + DT*S_t + DT*sum_{j<t} u_j^2 + DT*sum_{j<t} s0*DECAY^j
// with DT*sum s0*DECAY^j bounded by TAU*|s0|. Per segment g (64 steps),
// let K_g = |u0| + DT*max_{t in g}|S_t| + TAU*|s0| + c_g + eps, where c_g
// bounds the quadratic accumulation before segment g. If M_g >= K_g + BETA*M_g^2
// (checked explicitly in fp, M_g = 1.5*K_g), then |u_t| <= M_g throughout
// segment g by induction, and c_{g+1} = c_g + BETA*M_g^2. If additionally
// M_g < 50 (huge margin under v_th=100) for all g,i -> no spike can ever fire
// -> s is pure decay -> out[t] = s0*DECAY^(t+1). Any failed/NaN check falls
// through to the exact sequential simulator.
// ---------------------------------------------------------------------------

// K1 (2560 blocks x 256): segment prefix stats + output writer.
__global__ __launch_bounds__(256) void k_pre(const float* __restrict__ x,
                                             const float* __restrict__ s0,
                                             float* __restrict__ out,
                                             float* __restrict__ seg_sum,
                                             float* __restrict__ seg_mx,
                                             float* __restrict__ seg_mn) {
    const int b = (int)blockIdx.x;
    const int tid = (int)threadIdx.x;

    if (b < PRE_BLOCKS) {
        const int g = b >> 4;
        const int i = ((b & 15) << 8) + tid;
        const float* p = x + (size_t)g * SEG * N_NEUR + i;
        float run = 0.f, mx = 0.f, mn = 0.f;
        #pragma unroll
        for (int k = 0; k < SEG; ++k) {
            run += p[(size_t)k * N_NEUR];
            mx = fmaxf(mx, run);
            mn = fminf(mn, run);
        }
        seg_sum[g * N_NEUR + i] = run;
        seg_mx[g * N_NEUR + i] = mx;
        seg_mn[g * N_NEUR + i] = mn;
    } else {
        const int t = b - PRE_BLOCKS;
        const float scale = __powf(DECAY, (float)(t + 1));
        const float4* s4 = (const float4*)s0;
        float4* o4 = (float4*)out + (size_t)t * (N_NEUR / 4);
        #pragma unroll
        for (int p4 = 0; p4 < 4; ++p4) {
            const int c = p4 * 256 + tid;
            float4 v = s4[c];
            v.x *= scale; v.y *= scale; v.z *= scale; v.w *= scale;
            o4[c] = v;
        }
    }
}

// K2 (16 blocks x 256): per-neuron segment-wise bootstrap -> flags[block].
__global__ __launch_bounds__(256) void k_combine(const float* __restrict__ u0,
                                                 const float* __restrict__ s0,
                                                 const float* __restrict__ seg_sum,
                                                 const float* __restrict__ seg_mx,
                                                 const float* __restrict__ seg_mn,
                                                 int* __restrict__ flags) {
    __shared__ int sbad;
    const int tid = (int)threadIdx.x;
    if (tid == 0) sbad = 0;
    __syncthreads();

    const int i = (int)blockIdx.x * 256 + tid;
    const float base_term = fabsf(u0[i]) + TAU * fabsf(s0[i]) + 1e-3f;

    bool bad = false;
    float base = 0.f;     // running prefix sum at segment start
    float c = 0.f;        // accumulated quadratic bound DT*sum u^2
    #pragma unroll
    for (int g = 0; g < NSEG; ++g) {
        const float mx = base + seg_mx[g * N_NEUR + i];
        const float mn = base + seg_mn[g * N_NEUR + i];
        const float P = fmaxf(mx, -mn);            // max |prefix| in segment
        const float K = base_term + DT * P + c;
        const float M = 1.5f * K;
        bad |= !(M >= K + BETA * M * M);           // bootstrap check (NaN-safe)
        bad |= !(M < 50.0f);                       // spike margin check
        c += BETA * M * M;
        base += seg_sum[g * N_NEUR + i];
    }
    if (bad) atomicOr(&sbad, 1);
    __syncthreads();
    if (tid == 0) flags[blockIdx.x] = sbad;
}

// K3 (1 block x 1024): reduce flags; fast-exit, else exact simulation.
__global__ __launch_bounds__(1024) void k_slow(const float* __restrict__ x,
                                               const float* __restrict__ W,
                                               const float* __restrict__ u0,
                                               const float* __restrict__ s0,
                                               float* __restrict__ out,
                                               const int* __restrict__ flags) {
    __shared__ int any;
    const int tid = (int)threadIdx.x;
    if (tid == 0) any = 0;
    __syncthreads();
    if (tid < 16 && flags[tid] != 0) any = 1;
    __syncthreads();
    if (any == 0) return;                // expected path: fast exit

    __shared__ float u[N_NEUR];
    __shared__ float s[N_NEUR];
    __shared__ int list[N_NEUR];
    __shared__ int cnt;
    for (int m = tid; m < N_NEUR; m += 1024) { u[m] = u0[m]; s[m] = s0[m]; }
    if (tid == 0) cnt = 0;
    __syncthreads();
    for (int t = 0; t < T_STEPS; ++t) {
        #pragma unroll
        for (int q = 0; q < 4; ++q) {
            const int i = tid + q * 1024;
            const float ui = u[i];
            const bool spk = ui >= V_TH;
            float un = ui + DT * (ui * ui + x[(size_t)t * N_NEUR + i] + s[i]);
            if (spk) {
                int p = atomicAdd(&cnt, 1);
                list[p] = i;
                un = V_R;
            }
            u[i] = un;
        }
        __syncthreads();
        const int k = cnt;
        #pragma unroll
        for (int q = 0; q < 4; ++q) {
            const int i = tid + q * 1024;
            float acc = 0.f;
            for (int m = 0; m < k; ++m) acc += W[(size_t)i * N_NEUR + list[m]];
            const float sn = s[i] * DECAY + acc;
            s[i] = sn;
            out[(size_t)t * N_NEUR + i] = sn;
        }
        __syncthreads();
        if (tid == 0) cnt = 0;
        __syncthreads();
    }
}

// ---------------------------------------------------------------------------
// Fallback path (round-3) if ws is too small for seg arrays + flags.
// ---------------------------------------------------------------------------
#define NSCAN 64
#define CH 64
#define NCH (T_STEPS / CH)

__global__ __launch_bounds__(64, 1) void k_scan_fb(const float* __restrict__ x,
                                                   const float* __restrict__ u0,
                                                   const float* __restrict__ s0,
                                                   float* __restrict__ out,
                                                   int* __restrict__ flags) {
    const int b = (int)blockIdx.x;
    const int tid = (int)threadIdx.x;
    if (b >= NSCAN) {
        const int t = b - NSCAN;
        const float scale = __powf(DECAY, (float)(t + 1));
        const float4* s4 = (const float4*)s0;
        float4* o4 = (float4*)out + (size_t)t * (N_NEUR / 4);
        #pragma unroll
        for (int p = 0; p < 16; ++p) {
            const int c = p * 64 + tid;
            float4 v = s4[c];
            v.x *= scale; v.y *= scale; v.z *= scale; v.w *= scale;
            o4[c] = v;
        }
        return;
    }
    const int i = b * 64 + tid;
    const float* xp = x + i;
    float uu = u0[i], ss = s0[i], um = uu;
    float A[CH], B[CH], C[CH];
    auto loadch = [&](float (&dst)[CH], int ck) {
        const float* p = xp + (size_t)ck * CH * N_NEUR;
        #pragma unroll
        for (int k = 0; k < CH; ++k) dst[k] = p[(size_t)k * N_NEUR];
    };
    auto compch = [&](const float (&src)[CH]) {
        #pragma unroll
        for (int k = 0; k < CH; ++k) {
            um = fmaxf(um, uu);
            uu = fmaf(DT, fmaf(uu, uu, src[k] + ss), uu);
            ss *= DECAY;
        }
    };
    loadch(A, 0); loadch(B, 1);
    #pragma unroll 1
    for (int c = 0; c < NCH - 2; c += 3) {
        loadch(C, c + 2); compch(A);
        loadch(A, c + 3); compch(B);
        loadch(B, c + 4); compch(C);
    }
    compch(A); compch(B);
    const unsigned long long anyb = __ballot(um >= 50.0f);
    if (tid == 0) flags[b] = (anyb != 0ull) ? 1 : 0;
}

__global__ __launch_bounds__(1024) void k_slow_fb(const float* __restrict__ x,
                                                  const float* __restrict__ W,
                                                  const float* __restrict__ u0,
                                                  const float* __restrict__ s0,
                                                  float* __restrict__ out,
                                                  const int* __restrict__ flags) {
    __shared__ int any;
    const int tid = (int)threadIdx.x;
    if (tid == 0) any = 0;
    __syncthreads();
    if (tid < NSCAN && flags[tid] != 0) any = 1;
    __syncthreads();
    if (any == 0) return;
    __shared__ float u[N_NEUR];
    __shared__ float s[N_NEUR];
    __shared__ int list[N_NEUR];
    __shared__ int cnt;
    for (int m = tid; m < N_NEUR; m += 1024) { u[m] = u0[m]; s[m] = s0[m]; }
    if (tid == 0) cnt = 0;
    __syncthreads();
    for (int t = 0; t < T_STEPS; ++t) {
        #pragma unroll
        for (int q = 0; q < 4; ++q) {
            const int i = tid + q * 1024;
            const float ui = u[i];
            const bool spk = ui >= V_TH;
            float un = ui + DT * (ui * ui + x[(size_t)t * N_NEUR + i] + s[i]);
            if (spk) { int p = atomicAdd(&cnt, 1); list[p] = i; un = V_R; }
            u[i] = un;
        }
        __syncthreads();
        const int k = cnt;
        #pragma unroll
        for (int q = 0; q < 4; ++q) {
            const int i = tid + q * 1024;
            float acc = 0.f;
            for (int m = 0; m < k; ++m) acc += W[(size_t)i * N_NEUR + list[m]];
            const float sn = s[i] * DECAY + acc;
            s[i] = sn;
            out[(size_t)t * N_NEUR + i] = sn;
        }
        __syncthreads();
        if (tid == 0) cnt = 0;
        __syncthreads();
    }
}

// ---------------------------------------------------------------------------
extern "C" void kernel_launch(void* const* d_in, const int* in_sizes, int n_in,
                              void* d_out, int out_size, void* d_ws, size_t ws_size,
                              hipStream_t stream) {
    const float* x  = (const float*)d_in[0];   // [T, N]
    const float* W  = (const float*)d_in[1];   // [N, N]
    const float* u0 = (const float*)d_in[2];   // [N]
    const float* s0 = (const float*)d_in[3];   // [N]
    float* out = (float*)d_out;                // [T, N]

    const size_t seg_elems = (size_t)NSEG * N_NEUR;
    if (ws_size >= 3 * seg_elems * sizeof(float) + 64 * sizeof(int)) {
        float* seg_sum = (float*)d_ws;
        float* seg_mx  = seg_sum + seg_elems;
        float* seg_mn  = seg_mx + seg_elems;
        int* flags     = (int*)(seg_mn + seg_elems);
        k_pre<<<PRE_BLOCKS + T_STEPS, 256, 0, stream>>>(x, s0, out,
                                                        seg_sum, seg_mx, seg_mn);
        k_combine<<<16, 256, 0, stream>>>(u0, s0, seg_sum, seg_mx, seg_mn, flags);
        k_slow<<<1, 1024, 0, stream>>>(x, W, u0, s0, out, flags);
    } else {
        int* flags = (int*)d_ws;
        k_scan_fb<<<NSCAN + T_STEPS, 64, 0, stream>>>(x, u0, s0, out, flags);
        k_slow_fb<<<1, 1024, 0, stream>>>(x, W, u0, s0, out, flags);
    }
}

// Round 6
// 29.195 us; speedup vs baseline: 106.9130x; 1.5365x over previous
//
#include <hip/hip_runtime.h>

#define N_NEUR 4096
#define T_STEPS 2048
#define DT 0.001f
#define TAU 10.0f
#define V_TH 100.0f
#define V_R -100.0f
#define DECAY (1.0f - DT / TAU)   // 0.9999f

#define SEG 32                    // time steps per prefix sub-segment
#define NSEG (T_STEPS / SEG)      // 64 sub-segments
#define BETA (DT * (float)SEG)    // 0.032 — per-segment bootstrap constant
#define NF4 (N_NEUR / 4)          // 1024 float4 columns
#define PRE_B (NSEG * 4)          // 256 pre-blocks (64 subsegs x 4 stripes)

// ---------------------------------------------------------------------------
// Spike-impossibility proof (segment-wise bootstrap, per neuron):
// While no spike has occurred anywhere, exactly:
//   u_t = u0 + DT*S_t + DT*sum_{j<t} u_j^2 + (decay-sum of s0, |.| <= TAU|s0|)
// Per sub-segment g of 32 steps: K_g = |u0| + TAU|s0| + eps + DT*max_t|S_t| + c_g,
// M_g = 1.5*K_g. If (checked in fp) M_g >= K_g + BETA*M_g^2, then |u_t| <= M_g
// throughout segment g by induction; c_{g+1} = c_g + BETA*M_g^2. If also
// M_g < 50 (half of v_th, ~100x above the actual dynamics) for all g,i,
// no spike can ever fire -> s is pure decay -> out[t] = s0*DECAY^(t+1).
// Any failed / NaN check falls to the exact sequential simulator.
// ---------------------------------------------------------------------------

// K1 (2304 blocks x 256):
//  blocks 0..255    : prefix stats. Block b: subseg ss=b>>2, stripe st=b&3.
//                     Thread owns float4 column f4c = st*256+tid (4 neurons),
//                     rows [ss*32, ss*32+32). Loads ALL 32 float4 into L[]
//                     (breadth-first, 128 VGPR in flight) then runs the
//                     4 prefix chains. Stores sum (float4) + packed (mx,mn).
//  blocks 256..2303 : writer, out row t = b-256 := s0 * DECAY^(t+1).
__global__ __launch_bounds__(256, 1) void k_pre(const float* __restrict__ x,
                                                const float* __restrict__ s0,
                                                float* __restrict__ out,
                                                float* __restrict__ seg_sum,
                                                float* __restrict__ seg_mm) {
    const int b = (int)blockIdx.x;
    const int tid = (int)threadIdx.x;

    if (b < PRE_B) {
        const int ss = b >> 2;
        const int st = b & 3;
        const int f4c = st * 256 + tid;
        const float4* p = (const float4*)x + (size_t)ss * SEG * NF4 + f4c;

        float4 L[SEG];
        #pragma unroll
        for (int k = 0; k < SEG; ++k) L[k] = p[(size_t)k * NF4];   // phase 1: loads

        float4 run = {0.f, 0.f, 0.f, 0.f};
        float4 mx  = {0.f, 0.f, 0.f, 0.f};
        float4 mn  = {0.f, 0.f, 0.f, 0.f};
        #pragma unroll
        for (int k = 0; k < SEG; ++k) {                            // phase 2: chains
            run.x += L[k].x; mx.x = fmaxf(mx.x, run.x); mn.x = fminf(mn.x, run.x);
            run.y += L[k].y; mx.y = fmaxf(mx.y, run.y); mn.y = fminf(mn.y, run.y);
            run.z += L[k].z; mx.z = fmaxf(mx.z, run.z); mn.z = fminf(mn.z, run.z);
            run.w += L[k].w; mx.w = fmaxf(mx.w, run.w); mn.w = fminf(mn.w, run.w);
        }
        ((float4*)seg_sum)[(size_t)ss * NF4 + f4c] = run;
        // packed layout: mm[g][2*i] = mx_i, mm[g][2*i+1] = mn_i
        float4 a = {mx.x, mn.x, mx.y, mn.y};
        float4 c = {mx.z, mn.z, mx.w, mn.w};
        float4* mm4 = (float4*)seg_mm + (size_t)ss * (N_NEUR / 2) + (size_t)f4c * 2;
        mm4[0] = a;
        mm4[1] = c;
    } else {
        const int t = b - PRE_B;
        const float scale = powf(DECAY, (float)(t + 1));
        const float4* s4 = (const float4*)s0;
        float4* o4 = (float4*)out + (size_t)t * NF4;
        #pragma unroll
        for (int p4 = 0; p4 < 4; ++p4) {
            const int cidx = p4 * 256 + tid;
            float4 v = s4[cidx];
            v.x *= scale; v.y *= scale; v.z *= scale; v.w *= scale;
            o4[cidx] = v;
        }
    }
}

// K2 (16 blocks x 256): per-neuron bootstrap chain over 64 sub-segments.
__global__ __launch_bounds__(256) void k_combine(const float* __restrict__ u0,
                                                 const float* __restrict__ s0,
                                                 const float* __restrict__ seg_sum,
                                                 const float* __restrict__ seg_mm,
                                                 int* __restrict__ flags) {
    __shared__ int sbad;
    const int tid = (int)threadIdx.x;
    if (tid == 0) sbad = 0;
    __syncthreads();

    const int i = (int)blockIdx.x * 256 + tid;
    const float base_term = fabsf(u0[i]) + TAU * fabsf(s0[i]) + 1e-3f;
    const float2* mm2 = (const float2*)seg_mm;

    bool bad = false;
    float base = 0.f;     // running prefix sum at segment start
    float c = 0.f;        // accumulated quadratic bound DT*sum u^2
    #pragma unroll 4
    for (int g = 0; g < NSEG; ++g) {
        const float2 mm = mm2[(size_t)g * N_NEUR + i];
        const float mxv = base + mm.x;
        const float mnv = base + mm.y;
        const float P = fmaxf(mxv, -mnv);          // max |prefix| in segment
        const float K = base_term + DT * P + c;
        const float M = 1.5f * K;
        bad |= !(M >= K + BETA * M * M);           // bootstrap check (NaN-safe)
        bad |= !(M < 50.0f);                       // spike margin check
        c += BETA * M * M;
        base += seg_sum[(size_t)g * N_NEUR + i];
    }
    if (bad) atomicOr(&sbad, 1);
    __syncthreads();
    if (tid == 0) flags[blockIdx.x] = sbad;
}

// K3 (1 block x 1024): reduce flags; fast-exit, else exact simulation.
__global__ __launch_bounds__(1024) void k_slow(const float* __restrict__ x,
                                               const float* __restrict__ W,
                                               const float* __restrict__ u0,
                                               const float* __restrict__ s0,
                                               float* __restrict__ out,
                                               const int* __restrict__ flags) {
    __shared__ int any;
    const int tid = (int)threadIdx.x;
    if (tid == 0) any = 0;
    __syncthreads();
    if (tid < 16 && flags[tid] != 0) any = 1;
    __syncthreads();
    if (any == 0) return;                // expected path: fast exit

    __shared__ float u[N_NEUR];
    __shared__ float s[N_NEUR];
    __shared__ int list[N_NEUR];
    __shared__ int cnt;
    for (int m = tid; m < N_NEUR; m += 1024) { u[m] = u0[m]; s[m] = s0[m]; }
    if (tid == 0) cnt = 0;
    __syncthreads();
    for (int t = 0; t < T_STEPS; ++t) {
        #pragma unroll
        for (int q = 0; q < 4; ++q) {
            const int i = tid + q * 1024;
            const float ui = u[i];
            const bool spk = ui >= V_TH;
            float un = ui + DT * (ui * ui + x[(size_t)t * N_NEUR + i] + s[i]);
            if (spk) {
                int p = atomicAdd(&cnt, 1);
                list[p] = i;
                un = V_R;
            }
            u[i] = un;
        }
        __syncthreads();
        const int k = cnt;
        #pragma unroll
        for (int q = 0; q < 4; ++q) {
            const int i = tid + q * 1024;
            float acc = 0.f;
            for (int m = 0; m < k; ++m) acc += W[(size_t)i * N_NEUR + list[m]];
            const float sn = s[i] * DECAY + acc;
            s[i] = sn;
            out[(size_t)t * N_NEUR + i] = sn;
        }
        __syncthreads();
        if (tid == 0) cnt = 0;
        __syncthreads();
    }
}

// ---------------------------------------------------------------------------
// Fallback path (round-3 proven, 45 µs) if ws is too small for seg arrays.
// ---------------------------------------------------------------------------
#define NSCAN 64
#define CH 64
#define NCH (T_STEPS / CH)

__global__ __launch_bounds__(64, 1) void k_scan_fb(const float* __restrict__ x,
                                                   const float* __restrict__ u0,
                                                   const float* __restrict__ s0,
                                                   float* __restrict__ out,
                                                   int* __restrict__ flags) {
    const int b = (int)blockIdx.x;
    const int tid = (int)threadIdx.x;
    if (b >= NSCAN) {
        const int t = b - NSCAN;
        const float scale = powf(DECAY, (float)(t + 1));
        const float4* s4 = (const float4*)s0;
        float4* o4 = (float4*)out + (size_t)t * NF4;
        #pragma unroll
        for (int p = 0; p < 16; ++p) {
            const int c = p * 64 + tid;
            float4 v = s4[c];
            v.x *= scale; v.y *= scale; v.z *= scale; v.w *= scale;
            o4[c] = v;
        }
        return;
    }
    const int i = b * 64 + tid;
    const float* xp = x + i;
    float uu = u0[i], ss = s0[i], um = uu;
    float A[CH], B[CH], C[CH];
    auto loadch = [&](float (&dst)[CH], int ck) {
        const float* p = xp + (size_t)ck * CH * N_NEUR;
        #pragma unroll
        for (int k = 0; k < CH; ++k) dst[k] = p[(size_t)k * N_NEUR];
    };
    auto compch = [&](const float (&src)[CH]) {
        #pragma unroll
        for (int k = 0; k < CH; ++k) {
            um = fmaxf(um, uu);
            uu = fmaf(DT, fmaf(uu, uu, src[k] + ss), uu);
            ss *= DECAY;
        }
    };
    loadch(A, 0); loadch(B, 1);
    #pragma unroll 1
    for (int c = 0; c < NCH - 2; c += 3) {
        loadch(C, c + 2); compch(A);
        loadch(A, c + 3); compch(B);
        loadch(B, c + 4); compch(C);
    }
    compch(A); compch(B);
    const unsigned long long anyb = __ballot(um >= 50.0f);
    if (tid == 0) flags[b] = (anyb != 0ull) ? 1 : 0;
}

__global__ __launch_bounds__(1024) void k_slow_fb(const float* __restrict__ x,
                                                  const float* __restrict__ W,
                                                  const float* __restrict__ u0,
                                                  const float* __restrict__ s0,
                                                  float* __restrict__ out,
                                                  const int* __restrict__ flags) {
    __shared__ int any;
    const int tid = (int)threadIdx.x;
    if (tid == 0) any = 0;
    __syncthreads();
    if (tid < NSCAN && flags[tid] != 0) any = 1;
    __syncthreads();
    if (any == 0) return;
    __shared__ float u[N_NEUR];
    __shared__ float s[N_NEUR];
    __shared__ int list[N_NEUR];
    __shared__ int cnt;
    for (int m = tid; m < N_NEUR; m += 1024) { u[m] = u0[m]; s[m] = s0[m]; }
    if (tid == 0) cnt = 0;
    __syncthreads();
    for (int t = 0; t < T_STEPS; ++t) {
        #pragma unroll
        for (int q = 0; q < 4; ++q) {
            const int i = tid + q * 1024;
            const float ui = u[i];
            const bool spk = ui >= V_TH;
            float un = ui + DT * (ui * ui + x[(size_t)t * N_NEUR + i] + s[i]);
            if (spk) { int p = atomicAdd(&cnt, 1); list[p] = i; un = V_R; }
            u[i] = un;
        }
        __syncthreads();
        const int k = cnt;
        #pragma unroll
        for (int q = 0; q < 4; ++q) {
            const int i = tid + q * 1024;
            float acc = 0.f;
            for (int m = 0; m < k; ++m) acc += W[(size_t)i * N_NEUR + list[m]];
            const float sn = s[i] * DECAY + acc;
            s[i] = sn;
            out[(size_t)t * N_NEUR + i] = sn;
        }
        __syncthreads();
        if (tid == 0) cnt = 0;
        __syncthreads();
    }
}

// ---------------------------------------------------------------------------
extern "C" void kernel_launch(void* const* d_in, const int* in_sizes, int n_in,
                              void* d_out, int out_size, void* d_ws, size_t ws_size,
                              hipStream_t stream) {
    const float* x  = (const float*)d_in[0];   // [T, N]
    const float* W  = (const float*)d_in[1];   // [N, N]
    const float* u0 = (const float*)d_in[2];   // [N]
    const float* s0 = (const float*)d_in[3];   // [N]
    float* out = (float*)d_out;                // [T, N]

    const size_t sum_elems = (size_t)NSEG * N_NEUR;        // 256K floats
    const size_t mm_elems  = (size_t)NSEG * N_NEUR * 2;    // 512K floats
    if (ws_size >= (sum_elems + mm_elems) * sizeof(float) + 64 * sizeof(int)) {
        float* seg_sum = (float*)d_ws;
        float* seg_mm  = seg_sum + sum_elems;
        int* flags     = (int*)(seg_mm + mm_elems);
        k_pre<<<PRE_B + T_STEPS, 256, 0, stream>>>(x, s0, out, seg_sum, seg_mm);
        k_combine<<<16, 256, 0, stream>>>(u0, s0, seg_sum, seg_mm, flags);
        k_slow<<<1, 1024, 0, stream>>>(x, W, u0, s0, out, flags);
    } else {
        int* flags = (int*)d_ws;
        k_scan_fb<<<NSCAN + T_STEPS, 64, 0, stream>>>(x, u0, s0, out, flags);
        k_slow_fb<<<1, 1024, 0, stream>>>(x, W, u0, s0, out, flags);
    }
}

// Round 7
// 28.616 us; speedup vs baseline: 109.0757x; 1.0202x over previous
//
#include <hip/hip_runtime.h>

#define N_NEUR 4096
#define T_STEPS 2048
#define DT 0.001f
#define TAU 10.0f
#define V_TH 100.0f
#define V_R -100.0f
#define DECAY (1.0f - DT / TAU)   // 0.9999f

#define SEG 16                    // time steps per prefix sub-segment
#define NSEG (T_STEPS / SEG)      // 128 sub-segments
#define BETA (DT * (float)SEG)    // 0.016 — per-segment bootstrap constant
#define NF4 (N_NEUR / 4)          // 1024 float4 columns
#define PRE_B (NSEG * 4)          // 512 blocks (128 subsegs x 4 stripes)

// ---------------------------------------------------------------------------
// Spike-impossibility proof (segment-wise bootstrap, per neuron):
// While no spike has occurred anywhere, exactly:
//   u_t = u0 + DT*S_t + DT*sum_{j<t} u_j^2 + (decay-sum of s0, |.| <= TAU|s0|)
// Per sub-segment g (16 steps): K_g = |u0| + TAU|s0| + eps + DT*max_t|S_t| + c_g,
// M_g = 1.5*K_g. If (checked in fp) M_g >= K_g + BETA*M_g^2, then |u_t| <= M_g
// throughout segment g by induction; c_{g+1} = c_g + BETA*M_g^2. If also
// M_g < 50 (half of v_th, ~100x above actual dynamics) for all g,i -> no spike
// can ever fire -> s is pure decay -> out[t] = s0*DECAY^(t+1).
// Any failed / NaN check falls to the exact sequential simulator.
// ---------------------------------------------------------------------------

// K1 (512 blocks x 256): fused x-prefix-stats + out-writer.
// Block b: subseg ss=b>>2 (rows ss*16..+16), stripe st=b&3 (256 float4 cols).
// Order matters: s0 load FIRST, then the 16 x-loads, then the out-tile stores
// (compiler waits vmcnt(16) for s0 only -> stores overlap x-load latency),
// then the prefix chains consume x.
__global__ __launch_bounds__(256, 2) void k_pre(const float* __restrict__ x,
                                                const float* __restrict__ s0,
                                                float* __restrict__ out,
                                                float* __restrict__ seg_sum,
                                                float* __restrict__ seg_mm) {
    const int b = (int)blockIdx.x;
    const int tid = (int)threadIdx.x;
    const int ss = b >> 2;
    const int st = b & 3;
    const int f4c = st * 256 + tid;
    const int row0 = ss * SEG;

    // s0 first (oldest outstanding load)
    const float4 sv = ((const float4*)s0)[f4c];

    // issue all 16 x loads
    const float4* xp = (const float4*)x + (size_t)row0 * NF4 + f4c;
    float4 L[SEG];
    #pragma unroll
    for (int k = 0; k < SEG; ++k) L[k] = xp[(size_t)k * NF4];

    // out tile: needs only sv -> issues under x-load latency
    float scale = powf(DECAY, (float)(row0 + 1));
    float4* op = (float4*)out + (size_t)row0 * NF4 + f4c;
    #pragma unroll
    for (int k = 0; k < SEG; ++k) {
        float4 v = {sv.x * scale, sv.y * scale, sv.z * scale, sv.w * scale};
        op[(size_t)k * NF4] = v;
        scale *= DECAY;
    }

    // prefix chains over the 16 rows
    float4 run = {0.f, 0.f, 0.f, 0.f};
    float4 mx  = {0.f, 0.f, 0.f, 0.f};
    float4 mn  = {0.f, 0.f, 0.f, 0.f};
    #pragma unroll
    for (int k = 0; k < SEG; ++k) {
        run.x += L[k].x; mx.x = fmaxf(mx.x, run.x); mn.x = fminf(mn.x, run.x);
        run.y += L[k].y; mx.y = fmaxf(mx.y, run.y); mn.y = fminf(mn.y, run.y);
        run.z += L[k].z; mx.z = fmaxf(mx.z, run.z); mn.z = fminf(mn.z, run.z);
        run.w += L[k].w; mx.w = fmaxf(mx.w, run.w); mn.w = fminf(mn.w, run.w);
    }
    ((float4*)seg_sum)[(size_t)ss * NF4 + f4c] = run;
    // packed layout: mm[g][2*i] = mx_i, mm[g][2*i+1] = mn_i
    float4 a = {mx.x, mn.x, mx.y, mn.y};
    float4 c = {mx.z, mn.z, mx.w, mn.w};
    float4* mm4 = (float4*)seg_mm + (size_t)ss * (N_NEUR / 2) + (size_t)f4c * 2;
    mm4[0] = a;
    mm4[1] = c;
}

// K2 (16 blocks x 256): per-neuron bootstrap chain over 128 sub-segments.
// Chunked two-phase (16 breadth-first loads, then chain) to hide the
// cross-XCD / L3 latency of the seg arrays.
#define CSEG 16
__global__ __launch_bounds__(256) void k_combine(const float* __restrict__ u0,
                                                 const float* __restrict__ s0,
                                                 const float* __restrict__ seg_sum,
                                                 const float* __restrict__ seg_mm,
                                                 int* __restrict__ flags) {
    __shared__ int sbad;
    const int tid = (int)threadIdx.x;
    if (tid == 0) sbad = 0;
    __syncthreads();

    const int i = (int)blockIdx.x * 256 + tid;
    const float base_term = fabsf(u0[i]) + TAU * fabsf(s0[i]) + 1e-3f;
    const float2* mm2 = (const float2*)seg_mm;

    bool bad = false;
    float base = 0.f;     // running prefix sum at segment start
    float c = 0.f;        // accumulated quadratic bound DT*sum u^2
    #pragma unroll 1
    for (int c0 = 0; c0 < NSEG; c0 += CSEG) {
        float S[CSEG];
        float2 MM[CSEG];
        #pragma unroll
        for (int k = 0; k < CSEG; ++k) {
            S[k]  = seg_sum[(size_t)(c0 + k) * N_NEUR + i];
            MM[k] = mm2[(size_t)(c0 + k) * N_NEUR + i];
        }
        #pragma unroll
        for (int k = 0; k < CSEG; ++k) {
            const float mxv = base + MM[k].x;
            const float mnv = base + MM[k].y;
            const float P = fmaxf(mxv, -mnv);      // max |prefix| in segment
            const float K = base_term + DT * P + c;
            const float M = 1.5f * K;
            bad |= !(M >= K + BETA * M * M);       // bootstrap check (NaN-safe)
            bad |= !(M < 50.0f);                   // spike margin check
            c += BETA * M * M;
            base += S[k];
        }
    }
    if (bad) atomicOr(&sbad, 1);
    __syncthreads();
    if (tid == 0) flags[blockIdx.x] = sbad;
}

// K3 (1 block x 1024): reduce flags; fast-exit, else exact simulation.
__global__ __launch_bounds__(1024) void k_slow(const float* __restrict__ x,
                                               const float* __restrict__ W,
                                               const float* __restrict__ u0,
                                               const float* __restrict__ s0,
                                               float* __restrict__ out,
                                               const int* __restrict__ flags) {
    __shared__ int any;
    const int tid = (int)threadIdx.x;
    if (tid == 0) any = 0;
    __syncthreads();
    if (tid < 16 && flags[tid] != 0) any = 1;
    __syncthreads();
    if (any == 0) return;                // expected path: fast exit

    __shared__ float u[N_NEUR];
    __shared__ float s[N_NEUR];
    __shared__ int list[N_NEUR];
    __shared__ int cnt;
    for (int m = tid; m < N_NEUR; m += 1024) { u[m] = u0[m]; s[m] = s0[m]; }
    if (tid == 0) cnt = 0;
    __syncthreads();
    for (int t = 0; t < T_STEPS; ++t) {
        #pragma unroll
        for (int q = 0; q < 4; ++q) {
            const int i = tid + q * 1024;
            const float ui = u[i];
            const bool spk = ui >= V_TH;
            float un = ui + DT * (ui * ui + x[(size_t)t * N_NEUR + i] + s[i]);
            if (spk) {
                int p = atomicAdd(&cnt, 1);
                list[p] = i;
                un = V_R;
            }
            u[i] = un;
        }
        __syncthreads();
        const int k = cnt;
        #pragma unroll
        for (int q = 0; q < 4; ++q) {
            const int i = tid + q * 1024;
            float acc = 0.f;
            for (int m = 0; m < k; ++m) acc += W[(size_t)i * N_NEUR + list[m]];
            const float sn = s[i] * DECAY + acc;
            s[i] = sn;
            out[(size_t)t * N_NEUR + i] = sn;
        }
        __syncthreads();
        if (tid == 0) cnt = 0;
        __syncthreads();
    }
}

// ---------------------------------------------------------------------------
// Fallback path (round-3 proven) if ws is too small for seg arrays.
// ---------------------------------------------------------------------------
#define NSCAN 64
#define CH 64
#define NCH (T_STEPS / CH)

__global__ __launch_bounds__(64, 1) void k_scan_fb(const float* __restrict__ x,
                                                   const float* __restrict__ u0,
                                                   const float* __restrict__ s0,
                                                   float* __restrict__ out,
                                                   int* __restrict__ flags) {
    const int b = (int)blockIdx.x;
    const int tid = (int)threadIdx.x;
    if (b >= NSCAN) {
        const int t = b - NSCAN;
        const float scale = powf(DECAY, (float)(t + 1));
        const float4* s4 = (const float4*)s0;
        float4* o4 = (float4*)out + (size_t)t * NF4;
        #pragma unroll
        for (int p = 0; p < 16; ++p) {
            const int c = p * 64 + tid;
            float4 v = s4[c];
            v.x *= scale; v.y *= scale; v.z *= scale; v.w *= scale;
            o4[c] = v;
        }
        return;
    }
    const int i = b * 64 + tid;
    const float* xp = x + i;
    float uu = u0[i], ss = s0[i], um = uu;
    float A[CH], B[CH], C[CH];
    auto loadch = [&](float (&dst)[CH], int ck) {
        const float* p = xp + (size_t)ck * CH * N_NEUR;
        #pragma unroll
        for (int k = 0; k < CH; ++k) dst[k] = p[(size_t)k * N_NEUR];
    };
    auto compch = [&](const float (&src)[CH]) {
        #pragma unroll
        for (int k = 0; k < CH; ++k) {
            um = fmaxf(um, uu);
            uu = fmaf(DT, fmaf(uu, uu, src[k] + ss), uu);
            ss *= DECAY;
        }
    };
    loadch(A, 0); loadch(B, 1);
    #pragma unroll 1
    for (int c = 0; c < NCH - 2; c += 3) {
        loadch(C, c + 2); compch(A);
        loadch(A, c + 3); compch(B);
        loadch(B, c + 4); compch(C);
    }
    compch(A); compch(B);
    const unsigned long long anyb = __ballot(um >= 50.0f);
    if (tid == 0) flags[b] = (anyb != 0ull) ? 1 : 0;
}

__global__ __launch_bounds__(1024) void k_slow_fb(const float* __restrict__ x,
                                                  const float* __restrict__ W,
                                                  const float* __restrict__ u0,
                                                  const float* __restrict__ s0,
                                                  float* __restrict__ out,
                                                  const int* __restrict__ flags) {
    __shared__ int any;
    const int tid = (int)threadIdx.x;
    if (tid == 0) any = 0;
    __syncthreads();
    if (tid < NSCAN && flags[tid] != 0) any = 1;
    __syncthreads();
    if (any == 0) return;
    __shared__ float u[N_NEUR];
    __shared__ float s[N_NEUR];
    __shared__ int list[N_NEUR];
    __shared__ int cnt;
    for (int m = tid; m < N_NEUR; m += 1024) { u[m] = u0[m]; s[m] = s0[m]; }
    if (tid == 0) cnt = 0;
    __syncthreads();
    for (int t = 0; t < T_STEPS; ++t) {
        #pragma unroll
        for (int q = 0; q < 4; ++q) {
            const int i = tid + q * 1024;
            const float ui = u[i];
            const bool spk = ui >= V_TH;
            float un = ui + DT * (ui * ui + x[(size_t)t * N_NEUR + i] + s[i]);
            if (spk) { int p = atomicAdd(&cnt, 1); list[p] = i; un = V_R; }
            u[i] = un;
        }
        __syncthreads();
        const int k = cnt;
        #pragma unroll
        for (int q = 0; q < 4; ++q) {
            const int i = tid + q * 1024;
            float acc = 0.f;
            for (int m = 0; m < k; ++m) acc += W[(size_t)i * N_NEUR + list[m]];
            const float sn = s[i] * DECAY + acc;
            s[i] = sn;
            out[(size_t)t * N_NEUR + i] = sn;
        }
        __syncthreads();
        if (tid == 0) cnt = 0;
        __syncthreads();
    }
}

// ---------------------------------------------------------------------------
extern "C" void kernel_launch(void* const* d_in, const int* in_sizes, int n_in,
                              void* d_out, int out_size, void* d_ws, size_t ws_size,
                              hipStream_t stream) {
    const float* x  = (const float*)d_in[0];   // [T, N]
    const float* W  = (const float*)d_in[1];   // [N, N]
    const float* u0 = (const float*)d_in[2];   // [N]
    const float* s0 = (const float*)d_in[3];   // [N]
    float* out = (float*)d_out;                // [T, N]

    const size_t sum_elems = (size_t)NSEG * N_NEUR;        // 512K floats (2 MB)
    const size_t mm_elems  = (size_t)NSEG * N_NEUR * 2;    // 1M floats (4 MB)
    if (ws_size >= (sum_elems + mm_elems) * sizeof(float) + 64 * sizeof(int)) {
        float* seg_sum = (float*)d_ws;
        float* seg_mm  = seg_sum + sum_elems;
        int* flags     = (int*)(seg_mm + mm_elems);
        k_pre<<<PRE_B, 256, 0, stream>>>(x, s0, out, seg_sum, seg_mm);
        k_combine<<<16, 256, 0, stream>>>(u0, s0, seg_sum, seg_mm, flags);
        k_slow<<<1, 1024, 0, stream>>>(x, W, u0, s0, out, flags);
    } else {
        int* flags = (int*)d_ws;
        k_scan_fb<<<NSCAN + T_STEPS, 64, 0, stream>>>(x, u0, s0, out, flags);
        k_slow_fb<<<1, 1024, 0, stream>>>(x, W, u0, s0, out, flags);
    }
}